// Round 6
// baseline (339.990 us; speedup 1.0000x reference)
//
#include <hip/hip_runtime.h>
#include <stdint.h>

// ---------------------------------------------------------------------------
// MultiHeadedAttention (B=2,S=2048,D=1024,H=16,DK=64)
//   INPUTS fp32 (query,key,value,Wqkv,Wout) + int32 mask; OUTPUT fp32.
// R13:
//   * QKV GEMM reads fp32 activations DIRECTLY (fp32 LDS staging via
//     global_load_lds, in-register bf16 cvt at fragment read) -> the 24MB
//     bf16 activation copies + 72MB of cvt traffic are gone. prep now does
//     mask bits + 2 weight converts only. 4 -> 3+1 dispatches.
//   * QKV grid back to R11-best: 128x128 blocks, 768 blocks = 3/CU exactly
//     (R12's 384-block 64x128-wave config was a tail/occupancy regression).
//   * attn byte-identical to R8 (control rows).
// ---------------------------------------------------------------------------

typedef __bf16 bf16;
typedef __bf16 bf16x8 __attribute__((ext_vector_type(8)));
typedef __bf16 bf16x4 __attribute__((ext_vector_type(4)));
typedef float f32x4 __attribute__((ext_vector_type(4)));

#define MFMA16(a, b, c) __builtin_amdgcn_mfma_f32_16x16x32_bf16((a), (b), (c), 0, 0, 0)
#define EXP2(x) __builtin_amdgcn_exp2f(x)

static constexpr int BATCH = 2;
static constexpr int SEQ = 2048;
static constexpr int DIM = 1024;
static constexpr int DK = 64;
// q is pre-scaled by 1/sqrt(DK) * log2(e) in the QKV GEMM epilogue (z==0)
static constexpr float QSCALE = 0.125f * 1.44269504088896340736f;

// ---- async global->LDS, 16 B per lane -------------------------------------
__device__ inline void gload16(const void* g, void* l) {
  __builtin_amdgcn_global_load_lds((const __attribute__((address_space(1))) void*)g,
                                   (__attribute__((address_space(3))) void*)l, 16, 0, 0);
}

// ---- 8x fp32 -> bf16x8 ------------------------------------------------------
__device__ inline bf16x8 cvt8(const float* p) {
  const float4 a = *(const float4*)p;
  const float4 b = *(const float4*)(p + 4);
  bf16x8 v;
  v[0] = (bf16)a.x;
  v[1] = (bf16)a.y;
  v[2] = (bf16)a.z;
  v[3] = (bf16)a.w;
  v[4] = (bf16)b.x;
  v[5] = (bf16)b.y;
  v[6] = (bf16)b.z;
  v[7] = (bf16)b.w;
  return v;
}

// ---------------- prep: mask->bits + weight fp32->bf16 (one launch) --------
// blocks [0,8192): mask bits, 4 elems/thread (wave: 256 consecutive elems).
// blocks [8192,8704): Wqkv cvt; [8704,9216): Wout cvt.
__global__ __launch_bounds__(256) void prep_kernel(const int* __restrict__ mask,
                                                   unsigned long long* __restrict__ bits,
                                                   const float* __restrict__ swq,
                                                   const float* __restrict__ swo,
                                                   bf16* __restrict__ dwq,
                                                   bf16* __restrict__ dwo) {
  const int bid = blockIdx.x;
  const int tid = threadIdx.x;
  if (bid < 8192) {
    const int lane = tid & 63, wv = tid >> 6;
    const int ebase = (bid * 4 + wv) * 256;  // 256 consecutive mask elems/wave
    unsigned long long w[4];
#pragma unroll
    for (int j = 0; j < 4; ++j) {
      int m = mask[ebase + j * 64 + lane];
      w[j] = __ballot(m != 0);
    }
    if (lane == 0) {
#pragma unroll
      for (int j = 0; j < 4; ++j) bits[(ebase >> 6) + j] = w[j];
    }
    return;
  }
  int r = bid - 8192;
  const float* s = (r < 512) ? swq : swo;
  bf16* d = (r < 512) ? dwq : dwo;
  const int i = (r & 511) * 256 + tid;
  ((bf16x8*)d)[i] = cvt8(&s[8 * i]);
}

// ---------------- GEMM: C[M,1024](TC) = A[M,1024](TA) @ W[1024,1024]^T -----
// BMxBN block, 4 waves (2x2), wave (BM/2)x(BN/2), BK=32, linear LDS [rows][32],
// global_load_lds(16B) staging (fp32 A staged raw, cvt at frag read),
// 2-phase double-buffer, XCD-chunked bijective block swizzle.
template <int BM, int BN, int NBX, int NBY, int NBZ, int MINW, typename TA, typename TC>
__global__ __launch_bounds__(256, MINW) void gemm_bt_lds(
    const TA* __restrict__ A0, const TA* __restrict__ A1, const TA* __restrict__ A2,
    const bf16* __restrict__ W, TC* __restrict__ C0, TC* __restrict__ C1, TC* __restrict__ C2,
    float scale0) {
  constexpr int K = 1024, N = 1024;
  constexpr int MT = BM / 32, NT = BN / 32;  // frags per wave (m,n)
  constexpr bool AF32 = sizeof(TA) == 4;
  constexpr int PA = AF32 ? (BM / 32) : (BM / 64);  // A staging passes
  constexpr int PB = BN / 64;                       // B staging passes
  constexpr int NB = NBX * NBY * NBZ;
  __shared__ __align__(16) TA As[2][BM * 32];
  __shared__ __align__(16) bf16 Bs[2][BN * 32];

  // bijective XCD-chunked swizzle: hw-linear id -> logical id
  const int lin = blockIdx.x + NBX * (blockIdx.y + NBY * blockIdx.z);
  const int l = (lin & 7) * (NB / 8) + (lin >> 3);
  const int lx = l % NBX;
  const int ly = (l / NBX) % NBY;
  const int lz = l / (NBX * NBY);

  const TA* A = (lz == 0) ? A0 : (lz == 1) ? A1 : A2;
  TC* C = (lz == 0) ? C0 : (lz == 1) ? C1 : C2;
  const float sc = (lz == 0) ? scale0 : 1.0f;

  const int tid = threadIdx.x;
  const int lane = tid & 63;
  const int wv = tid >> 6;
  const int wm = wv >> 1, wn = wv & 1;
  const int lrow = lane & 15, quad = lane >> 4;
  const int m0 = ly * BM, n0 = lx * BN;

  // staging addressing (16B per lane, LDS dest linear = tid*16B per pass)
  const int rA = AF32 ? (tid >> 3) : (tid >> 2);
  const int cA = AF32 ? ((tid & 7) * 4) : ((tid & 3) * 8);
  constexpr int ROWSA = AF32 ? 32 : 64;             // rows per A pass
  constexpr int ELEMA = AF32 ? 1024 : 2048;         // LDS elems per A pass
  constexpr int EPTA = AF32 ? 4 : 8;                // LDS elems per thread
  const int rB = tid >> 2, cB = (tid & 3) * 8;
  const TA* pa[PA];
  const bf16* pb[PB];
#pragma unroll
  for (int p = 0; p < PA; ++p) pa[p] = A + (size_t)(m0 + p * ROWSA + rA) * K + cA;
#pragma unroll
  for (int p = 0; p < PB; ++p) pb[p] = W + (size_t)(n0 + p * 64 + rB) * K + cB;

  const f32x4 fz = {0.f, 0.f, 0.f, 0.f};
  f32x4 acc[MT][NT];
#pragma unroll
  for (int i = 0; i < MT; ++i)
#pragma unroll
    for (int j = 0; j < NT; ++j) acc[i][j] = fz;

  // prologue: stage tile 0 into buffer 0
#pragma unroll
  for (int p = 0; p < PA; ++p) gload16(pa[p], &As[0][p * ELEMA + tid * EPTA]);
#pragma unroll
  for (int p = 0; p < PB; ++p) gload16(pb[p], &Bs[0][p * 2048 + tid * 8]);
  __syncthreads();  // vmcnt(0): tile 0 resident

  for (int t = 0; t < K / 32; ++t) {
    const int cur = t & 1;
    if (t + 1 < K / 32) {  // issue next-tile prefetch into the other buffer
      const int k1 = (t + 1) * 32;
#pragma unroll
      for (int p = 0; p < PA; ++p) gload16(pa[p] + k1, &As[cur ^ 1][p * ELEMA + tid * EPTA]);
#pragma unroll
      for (int p = 0; p < PB; ++p) gload16(pb[p] + k1, &Bs[cur ^ 1][p * 2048 + tid * 8]);
    }
    bf16x8 af[MT], bfr[NT];
#pragma unroll
    for (int mt = 0; mt < MT; ++mt) {
      const int row = wm * (BM / 2) + mt * 16 + lrow;
      if constexpr (AF32) {
        af[mt] = cvt8((const float*)&As[cur][row * 32 + quad * 8]);
      } else {
        af[mt] = *(const bf16x8*)(&As[cur][row * 32 + quad * 8]);
      }
    }
#pragma unroll
    for (int nt = 0; nt < NT; ++nt)
      bfr[nt] = *(const bf16x8*)(&Bs[cur][(wn * (BN / 2) + nt * 16 + lrow) * 32 + quad * 8]);
#pragma unroll
    for (int mt = 0; mt < MT; ++mt)
#pragma unroll
      for (int nt = 0; nt < NT; ++nt) acc[mt][nt] = MFMA16(af[mt], bfr[nt], acc[mt][nt]);
    __syncthreads();  // drains this step's prefetch + all ds reads
  }

#pragma unroll
  for (int mt = 0; mt < MT; ++mt) {
    const int gm = m0 + wm * (BM / 2) + mt * 16 + quad * 4;
#pragma unroll
    for (int nt = 0; nt < NT; ++nt) {
      const int gn = n0 + wn * (BN / 2) + nt * 16 + lrow;
#pragma unroll
      for (int r = 0; r < 4; ++r) C[(size_t)(gm + r) * N + gn] = (TC)(acc[mt][nt][r] * sc);
    }
  }
}

// ---------------- flash attention, transposed-S form (R8 exact) ------------
// BQ=128/block (4 waves x 32 q-rows), K-tiles of 64, max-free softmax.
// S^T = K·Q^T: per-lane P = 4 consecutive keys at one q-row -> b64 stores.
// Double-buffered K/V LDS (Qs reused as buffer 1), one barrier per tile.
__global__ __launch_bounds__(256, 2) void attn_kernel(const bf16* __restrict__ Qg,
                                                      const bf16* __restrict__ Kg,
                                                      const bf16* __restrict__ Vg,
                                                      const unsigned* __restrict__ bits,
                                                      bf16* __restrict__ Y) {
  constexpr int LQ = 72;
  __shared__ bf16 Qs[128 * LQ];  // after qf extraction: K/V buffer 1
  __shared__ bf16 Ks[64 * LQ];
  __shared__ bf16 Vts[64 * LQ];
  __shared__ bf16 Ps[4][32 * LQ];

  const int tid = threadIdx.x;
  const int lane = tid & 63;
  const int wv = tid >> 6;
  const int lrow = lane & 15, quad = lane >> 4;
  const int bh = blockIdx.y;
  const int b = bh >> 4, h = bh & 15;
  const int q0 = blockIdx.x * 128;

  const bf16* Qh = Qg + (size_t)bh * (SEQ * DK);
  const bf16* Kh = Kg + (size_t)bh * (SEQ * DK);
  const bf16* Vh = Vg + (size_t)bh * (SEQ * DK);

  // ---- stage Q tile (128x64, pre-scaled by QSCALE) ----
#pragma unroll
  for (int i = 0; i < 4; ++i) {
    int s = tid + i * 256;
    int row = s >> 3, c8 = (s & 7) * 8;
    *(uint4*)(&Qs[row * LQ + c8]) = *(const uint4*)(Qh + (size_t)(q0 + row) * DK + c8);
  }

  // ---- K/V prefetch-register plumbing ----
  const int krow = tid >> 3;  // 0..31 (second stripe: +32)
  const int kc8 = (tid & 7) * 8;
  const bf16* pk0 = Kh + (size_t)krow * DK + kc8;
  const bf16* pk1 = Kh + (size_t)(krow + 32) * DK + kc8;
  const int vn2 = tid & 31;   // dk-pair index
  const int vk2b = tid >> 5;  // key-pair base (k2 = vk2b + i*8)
  const bf16* pv0 = Vh + (size_t)(vk2b + 0) * 2 * DK + vn2 * 2;
  const bf16* pv1 = Vh + (size_t)(vk2b + 8) * 2 * DK + vn2 * 2;
  const bf16* pv2 = Vh + (size_t)(vk2b + 16) * 2 * DK + vn2 * 2;
  const bf16* pv3 = Vh + (size_t)(vk2b + 24) * 2 * DK + vn2 * 2;

  uint4 kr0, kr1;
  uint32_t va[4], vb[4];

  // tile 0 -> buffer 0 (Ks/Vts; independent of Qs)
  kr0 = *(const uint4*)(pk0);
  kr1 = *(const uint4*)(pk1);
  va[0] = *(const uint32_t*)(pv0);
  vb[0] = *(const uint32_t*)(pv0 + DK);
  va[1] = *(const uint32_t*)(pv1);
  vb[1] = *(const uint32_t*)(pv1 + DK);
  va[2] = *(const uint32_t*)(pv2);
  vb[2] = *(const uint32_t*)(pv2 + DK);
  va[3] = *(const uint32_t*)(pv3);
  vb[3] = *(const uint32_t*)(pv3 + DK);
  *(uint4*)(&Ks[krow * LQ + kc8]) = kr0;
  *(uint4*)(&Ks[(krow + 32) * LQ + kc8]) = kr1;
#pragma unroll
  for (int i = 0; i < 4; ++i) {
    uint32_t t0 = (va[i] & 0xffffu) | (vb[i] << 16);
    uint32_t t1 = (va[i] >> 16) | (vb[i] & 0xffff0000u);
    *(uint32_t*)(&Vts[(vn2 * 2) * LQ + (vk2b + i * 8) * 2]) = t0;
    *(uint32_t*)(&Vts[(vn2 * 2 + 1) * LQ + (vk2b + i * 8) * 2]) = t1;
  }
  __syncthreads();  // Q + tile0 staged

  bf16x8 qf[2][2];  // B-frag for S^T: [q-row tile][ks]
#pragma unroll
  for (int nt = 0; nt < 2; ++nt)
#pragma unroll
    for (int ks = 0; ks < 2; ++ks)
      qf[nt][ks] = *(const bf16x8*)(&Qs[(wv * 32 + nt * 16 + lrow) * LQ + ks * 32 + quad * 8]);
  __syncthreads();  // all qf reads done -> Qs reusable as buffer 1

  const f32x4 fz = {0.f, 0.f, 0.f, 0.f};
  f32x4 of_t[4][2];  // O^T: [dk-tile][q-row-tile]
#pragma unroll
  for (int i = 0; i < 4; ++i)
#pragma unroll
    for (int j = 0; j < 2; ++j) of_t[i][j] = fz;
  float lsum[2] = {0.f, 0.f};  // per-lane partial row sums (q-row nt*16+lrow)

  const unsigned* bitrow = bits + (size_t)b * SEQ * (SEQ / 32);

  for (int kt = 0; kt < 32; ++kt) {
    const int cur = kt & 1;
    bf16* kb = cur ? Qs : Ks;
    bf16* vbuf = cur ? (Qs + 64 * LQ) : Vts;
    // prefetch next tile (global; overlaps the whole compute body)
    if (kt + 1 < 32) {
      const size_t adv = (size_t)(kt + 1) * 64 * DK;
      kr0 = *(const uint4*)(pk0 + adv);
      kr1 = *(const uint4*)(pk1 + adv);
      va[0] = *(const uint32_t*)(pv0 + adv);
      vb[0] = *(const uint32_t*)(pv0 + adv + DK);
      va[1] = *(const uint32_t*)(pv1 + adv);
      vb[1] = *(const uint32_t*)(pv1 + adv + DK);
      va[2] = *(const uint32_t*)(pv2 + adv);
      vb[2] = *(const uint32_t*)(pv2 + adv + DK);
      va[3] = *(const uint32_t*)(pv3 + adv);
      vb[3] = *(const uint32_t*)(pv3 + adv + DK);
    }
    // mask: one 64-bit word per q-row covers this tile's 64 keys
    uint2 mwn[2];
#pragma unroll
    for (int nt = 0; nt < 2; ++nt) {
      int row = q0 + wv * 32 + nt * 16 + lrow;
      mwn[nt] = *(const uint2*)(bitrow + (size_t)row * (SEQ / 32) + kt * 2);
    }

    // ---- S^T = K @ Q^T (A = K-frag, B = Q-frag) ----
    f32x4 st[4][2];
#pragma unroll
    for (int mt = 0; mt < 4; ++mt)
#pragma unroll
      for (int nt = 0; nt < 2; ++nt) st[mt][nt] = fz;
#pragma unroll
    for (int ks = 0; ks < 2; ++ks) {
#pragma unroll
      for (int mt = 0; mt < 4; ++mt) {
        bf16x8 kfv = *(const bf16x8*)(kb + (mt * 16 + lrow) * LQ + ks * 32 + quad * 8);
#pragma unroll
        for (int nt = 0; nt < 2; ++nt) st[mt][nt] = MFMA16(kfv, qf[nt][ks], st[mt][nt]);
      }
    }

    // ---- max-free softmax; packed b64 P stores ----
    // lane's values: q-row = nt*16+lrow, keys = mt*16+quad*4+{0..3}
#pragma unroll
    for (int nt = 0; nt < 2; ++nt) {
      uint32_t ux = mwn[nt].x >> (quad * 4);
      uint32_t uy = mwn[nt].y >> (quad * 4);
      float psum = 0.f;
#pragma unroll
      for (int mt = 0; mt < 4; ++mt) {
        uint32_t u = (mt & 2) ? uy : ux;
        int sh = (mt & 1) << 4;
        bf16x4 pk;
#pragma unroll
        for (int r = 0; r < 4; ++r) {
          float p = EXP2(st[mt][nt][r]);
          p = ((u >> (sh + r)) & 1u) ? p : 0.f;
          psum += p;
          pk[r] = (bf16)p;
        }
        *(bf16x4*)(&Ps[wv][(nt * 16 + lrow) * LQ + mt * 16 + quad * 4]) = pk;
      }
      lsum[nt] += psum;
    }

    // ---- O^T += V^T @ P^T : A = Vt-frag, B = P-frag (both b128) ----
#pragma unroll
    for (int ks = 0; ks < 2; ++ks) {
      bf16x8 avf[4], bpf[2];
#pragma unroll
      for (int dkt = 0; dkt < 4; ++dkt)
        avf[dkt] = *(const bf16x8*)(vbuf + (dkt * 16 + lrow) * LQ + ks * 32 + quad * 8);
#pragma unroll
      for (int rt = 0; rt < 2; ++rt)
        bpf[rt] = *(const bf16x8*)(&Ps[wv][(rt * 16 + lrow) * LQ + ks * 32 + quad * 8]);
#pragma unroll
      for (int dkt = 0; dkt < 4; ++dkt)
#pragma unroll
        for (int rt = 0; rt < 2; ++rt) of_t[dkt][rt] = MFMA16(avf[dkt], bpf[rt], of_t[dkt][rt]);
    }

    // stage next tile into the other buffer
    if (kt + 1 < 32) {
      bf16* kbn = cur ? Ks : Qs;
      bf16* vbn = cur ? Vts : (Qs + 64 * LQ);
      *(uint4*)(kbn + krow * LQ + kc8) = kr0;
      *(uint4*)(kbn + (krow + 32) * LQ + kc8) = kr1;
#pragma unroll
      for (int i = 0; i < 4; ++i) {
        uint32_t t0 = (va[i] & 0xffffu) | (vb[i] << 16);
        uint32_t t1 = (va[i] >> 16) | (vb[i] & 0xffff0000u);
        *(uint32_t*)(vbn + (vn2 * 2) * LQ + (vk2b + i * 8) * 2) = t0;
        *(uint32_t*)(vbn + (vn2 * 2 + 1) * LQ + (vk2b + i * 8) * 2) = t1;
      }
    }
    __syncthreads();  // single barrier per tile
  }

  // ---- row-sum: reduce per-lane partials across quads (2 shuffles) ----
  float linv[2];
#pragma unroll
  for (int nt = 0; nt < 2; ++nt) {
    float v = lsum[nt];
    v += __shfl_xor(v, 16);
    v += __shfl_xor(v, 32);
    linv[nt] = 1.0f / fmaxf(v, 1e-20f);
  }

  // ---- epilogue: O^T C-layout col = q-row (lrow), row = dk (quad*4+j) ----
#pragma unroll
  for (int dkt = 0; dkt < 4; ++dkt)
#pragma unroll
    for (int rt = 0; rt < 2; ++rt) {
      bf16x4 o;
#pragma unroll
      for (int j = 0; j < 4; ++j) o[j] = (bf16)(of_t[dkt][rt][j] * linv[rt]);
      const int row = q0 + wv * 32 + rt * 16 + lrow;
      *(bf16x4*)(&Y[((size_t)b * SEQ + row) * DIM + h * 64 + dkt * 16 + quad * 4]) = o;
    }
}

// ---------------------------------------------------------------------------
extern "C" void kernel_launch(void* const* d_in, const int* in_sizes, int n_in,
                              void* d_out, int out_size, void* d_ws, size_t ws_size,
                              hipStream_t stream) {
  const float* query = (const float*)d_in[0];
  const float* key = (const float*)d_in[1];
  const float* value = (const float*)d_in[2];
  const float* Wqkv = (const float*)d_in[3];
  const float* Wout = (const float*)d_in[4];
  const int* mask = (const int*)d_in[5];
  float* out = (float*)d_out;

  // workspace map (37 MB): no activation copies anymore
  char* ws = (char*)d_ws;
  bf16* Wq = (bf16*)(ws);              //  2 MB  bf16 Wqkv
  bf16* Wo = (bf16*)(ws + 2097152);    //  2 MB  bf16 Wout
  bf16* q = (bf16*)(ws + 4194304);     //  8 MB  projected q (pre-scaled)
  bf16* k = (bf16*)(ws + 12582912);    //  8 MB
  bf16* v = (bf16*)(ws + 20971520);    //  8 MB
  bf16* y = (bf16*)(ws + 29360128);    //  8 MB  attn out
  unsigned long long* bits64 = (unsigned long long*)(ws + 37748736);  // 1 MB

  // 1) prep: mask->bits + weight fp32->bf16 converts
  prep_kernel<<<9216, 256, 0, stream>>>(mask, bits64, Wqkv, Wout, Wq, Wo);

  // 2) fused QKV projection straight from fp32 inputs (q scaled, z==0 only)
  //    128x128 blocks, 768 blocks = 3/CU (R11-best grid), fp32 A staging
  gemm_bt_lds<128, 128, 8, 32, 3, 3, float, bf16>
      <<<dim3(8, 32, 3), 256, 0, stream>>>(query, key, value, Wq, q, k, v, QSCALE);

  // 3) flash attention (16 q-tiles x 32 heads)
  attn_kernel<<<dim3(16, 32), 256, 0, stream>>>(q, k, v, (const unsigned*)bits64, y);

  // 4) output projection -> fp32 out; 64x128 blocks (512 blocks, 2/CU)
  gemm_bt_lds<64, 128, 8, 64, 1, 2, bf16, float>
      <<<dim3(8, 64, 1), 256, 0, stream>>>(y, y, y, Wo, out, out, out, 1.0f);
}

// Round 7
// 260.722 us; speedup vs baseline: 1.3040x; 1.3040x over previous
//
#include <hip/hip_runtime.h>
#include <stdint.h>

// ---------------------------------------------------------------------------
// MultiHeadedAttention (B=2,S=2048,D=1024,H=16,DK=64)
//   INPUTS fp32 (query,key,value,Wqkv,Wout) + int32 mask; OUTPUT fp32.
// R14:
//   * GEMMs: revert to bf16-A staging (R13's fp32-A frag reads = row stride
//     0 mod 128B -> 7.0e7 conflict-cycles = 75% of a 151us kernel).
//     prep converts activations + weights again (R12 fused form).
//   * attn v3: BQ=64 -> 1024 blocks = 4/CU (was 512 = 2/CU, 44% idle).
//     Q frags direct global->reg (no Qs LDS), single K/V buffer with
//     2 barriers/tile, LDS 55.3 -> 27.6KB, launch_bounds(256,4).
// ---------------------------------------------------------------------------

typedef __bf16 bf16;
typedef __bf16 bf16x8 __attribute__((ext_vector_type(8)));
typedef __bf16 bf16x4 __attribute__((ext_vector_type(4)));
typedef float f32x4 __attribute__((ext_vector_type(4)));

#define MFMA16(a, b, c) __builtin_amdgcn_mfma_f32_16x16x32_bf16((a), (b), (c), 0, 0, 0)
#define EXP2(x) __builtin_amdgcn_exp2f(x)

static constexpr int BATCH = 2;
static constexpr int SEQ = 2048;
static constexpr int DIM = 1024;
static constexpr int DK = 64;
// q is pre-scaled by 1/sqrt(DK) * log2(e) in the QKV GEMM epilogue (z==0)
static constexpr float QSCALE = 0.125f * 1.44269504088896340736f;

// ---- async global->LDS, 16 B per lane -------------------------------------
__device__ inline void gload16(const void* g, void* l) {
  __builtin_amdgcn_global_load_lds((const __attribute__((address_space(1))) void*)g,
                                   (__attribute__((address_space(3))) void*)l, 16, 0, 0);
}

// ---------------- prep: mask->bits + fp32->bf16 converts (one launch) ------
// blocks [0,8192): mask bits, 4 elems/thread (wave: 256 consecutive elems).
// blocks [8192,14336): activation cvt (2048 blocks each for q,k,v).
// blocks [14336,15360): weight cvt (512 blocks each for Wqkv,Wout).
__global__ __launch_bounds__(256) void prep_kernel(
    const int* __restrict__ mask, unsigned long long* __restrict__ bits,
    const float* __restrict__ sq, const float* __restrict__ sk, const float* __restrict__ sv,
    const float* __restrict__ swq, const float* __restrict__ swo,
    bf16* __restrict__ dq, bf16* __restrict__ dk, bf16* __restrict__ dv,
    bf16* __restrict__ dwq, bf16* __restrict__ dwo) {
  const int bid = blockIdx.x;
  const int tid = threadIdx.x;
  if (bid < 8192) {
    const int lane = tid & 63, wv = tid >> 6;
    const int ebase = (bid * 4 + wv) * 256;  // 256 consecutive mask elems/wave
    unsigned long long w[4];
#pragma unroll
    for (int j = 0; j < 4; ++j) {
      int m = mask[ebase + j * 64 + lane];
      w[j] = __ballot(m != 0);
    }
    if (lane == 0) {
#pragma unroll
      for (int j = 0; j < 4; ++j) bits[(ebase >> 6) + j] = w[j];
    }
    return;
  }
  int r = bid - 8192;
  const float* s;
  bf16* d;
  int i;
  if (r < 6144) {
    s = (r < 2048) ? sq : (r < 4096) ? sk : sv;
    d = (r < 2048) ? dq : (r < 4096) ? dk : dv;
    i = (r & 2047) * 256 + tid;
  } else {
    r -= 6144;
    s = (r < 512) ? swq : swo;
    d = (r < 512) ? dwq : dwo;
    i = (r & 511) * 256 + tid;
  }
  const float4 a = ((const float4*)s)[2 * i];
  const float4 b = ((const float4*)s)[2 * i + 1];
  bf16x8 v;
  v[0] = (bf16)a.x;
  v[1] = (bf16)a.y;
  v[2] = (bf16)a.z;
  v[3] = (bf16)a.w;
  v[4] = (bf16)b.x;
  v[5] = (bf16)b.y;
  v[6] = (bf16)b.z;
  v[7] = (bf16)b.w;
  ((bf16x8*)d)[i] = v;
}

// ---------------- GEMM: C[M,1024](TC) = A[M,1024](bf16) @ W[1024,1024]^T ---
// BMxBN block, 4 waves (2x2), wave (BM/2)x(BN/2), BK=32, linear LDS [rows][32],
// global_load_lds(16B) staging, 2-phase double-buffer, XCD-chunked swizzle.
template <int BM, int BN, int NBX, int NBY, int NBZ, int MINW, typename TC>
__global__ __launch_bounds__(256, MINW) void gemm_bt_lds(
    const bf16* __restrict__ A0, const bf16* __restrict__ A1, const bf16* __restrict__ A2,
    const bf16* __restrict__ W, TC* __restrict__ C0, TC* __restrict__ C1, TC* __restrict__ C2,
    float scale0) {
  constexpr int K = 1024, N = 1024;
  constexpr int MT = BM / 32, NT = BN / 32;  // frags per wave (m,n)
  constexpr int PA = BM / 64, PB = BN / 64;  // 64-row staging passes
  constexpr int NB = NBX * NBY * NBZ;
  __shared__ __align__(16) bf16 As[2][BM * 32];
  __shared__ __align__(16) bf16 Bs[2][BN * 32];

  // bijective XCD-chunked swizzle: hw-linear id -> logical id
  const int lin = blockIdx.x + NBX * (blockIdx.y + NBY * blockIdx.z);
  const int l = (lin & 7) * (NB / 8) + (lin >> 3);
  const int lx = l % NBX;
  const int ly = (l / NBX) % NBY;
  const int lz = l / (NBX * NBY);

  const bf16* A = (lz == 0) ? A0 : (lz == 1) ? A1 : A2;
  TC* C = (lz == 0) ? C0 : (lz == 1) ? C1 : C2;
  const float sc = (lz == 0) ? scale0 : 1.0f;

  const int tid = threadIdx.x;
  const int lane = tid & 63;
  const int wv = tid >> 6;
  const int wm = wv >> 1, wn = wv & 1;
  const int lrow = lane & 15, quad = lane >> 4;
  const int m0 = ly * BM, n0 = lx * BN;

  // staging: thread t covers row (t>>2) of each 64-row stripe, 8 bf16 at (t&3)*8
  const int r0 = tid >> 2, c0 = (tid & 3) * 8;
  const bf16* pa[PA];
  const bf16* pb[PB];
#pragma unroll
  for (int p = 0; p < PA; ++p) pa[p] = A + (size_t)(m0 + p * 64 + r0) * K + c0;
#pragma unroll
  for (int p = 0; p < PB; ++p) pb[p] = W + (size_t)(n0 + p * 64 + r0) * K + c0;

  const f32x4 fz = {0.f, 0.f, 0.f, 0.f};
  f32x4 acc[MT][NT];
#pragma unroll
  for (int i = 0; i < MT; ++i)
#pragma unroll
    for (int j = 0; j < NT; ++j) acc[i][j] = fz;

  // prologue: stage tile 0 into buffer 0
#pragma unroll
  for (int p = 0; p < PA; ++p) gload16(pa[p], &As[0][p * 2048 + tid * 8]);
#pragma unroll
  for (int p = 0; p < PB; ++p) gload16(pb[p], &Bs[0][p * 2048 + tid * 8]);
  __syncthreads();  // vmcnt(0): tile 0 resident

  for (int t = 0; t < K / 32; ++t) {
    const int cur = t & 1;
    if (t + 1 < K / 32) {  // issue next-tile prefetch into the other buffer
      const int k1 = (t + 1) * 32;
#pragma unroll
      for (int p = 0; p < PA; ++p) gload16(pa[p] + k1, &As[cur ^ 1][p * 2048 + tid * 8]);
#pragma unroll
      for (int p = 0; p < PB; ++p) gload16(pb[p] + k1, &Bs[cur ^ 1][p * 2048 + tid * 8]);
    }
    bf16x8 af[MT], bfr[NT];
#pragma unroll
    for (int mt = 0; mt < MT; ++mt)
      af[mt] = *(const bf16x8*)(&As[cur][(wm * (BM / 2) + mt * 16 + lrow) * 32 + quad * 8]);
#pragma unroll
    for (int nt = 0; nt < NT; ++nt)
      bfr[nt] = *(const bf16x8*)(&Bs[cur][(wn * (BN / 2) + nt * 16 + lrow) * 32 + quad * 8]);
#pragma unroll
    for (int mt = 0; mt < MT; ++mt)
#pragma unroll
      for (int nt = 0; nt < NT; ++nt) acc[mt][nt] = MFMA16(af[mt], bfr[nt], acc[mt][nt]);
    __syncthreads();  // drains this step's prefetch + all ds reads
  }

#pragma unroll
  for (int mt = 0; mt < MT; ++mt) {
    const int gm = m0 + wm * (BM / 2) + mt * 16 + quad * 4;
#pragma unroll
    for (int nt = 0; nt < NT; ++nt) {
      const int gn = n0 + wn * (BN / 2) + nt * 16 + lrow;
#pragma unroll
      for (int r = 0; r < 4; ++r) C[(size_t)(gm + r) * N + gn] = (TC)(acc[mt][nt][r] * sc);
    }
  }
}

// ---------------- flash attention v3: BQ=64, 1024 blocks, 4/CU -------------
// 4 waves x 16 q-rows each; K-tiles of 64; max-free softmax; S^T = K·Q^T.
// Q frags direct global->reg; single K/V LDS buffer (2 barriers/tile);
// register prefetch of next K/V tile overlaps the whole compute body.
__global__ __launch_bounds__(256, 4) void attn_kernel(const bf16* __restrict__ Qg,
                                                      const bf16* __restrict__ Kg,
                                                      const bf16* __restrict__ Vg,
                                                      const unsigned* __restrict__ bits,
                                                      bf16* __restrict__ Y) {
  constexpr int LQ = 72;
  __shared__ bf16 Ks[64 * LQ];       //  9216 B
  __shared__ bf16 Vts[64 * LQ];      //  9216 B
  __shared__ bf16 Ps[4][16 * LQ];    //  9216 B  (total 27.6 KB -> 4+ blocks/CU)

  const int tid = threadIdx.x;
  const int lane = tid & 63;
  const int wv = tid >> 6;
  const int lrow = lane & 15, quad = lane >> 4;
  const int bh = blockIdx.y;
  const int b = bh >> 4, h = bh & 15;
  const int q0 = blockIdx.x * 64;
  const int qrow = q0 + wv * 16 + lrow;  // this lane's q-row

  const bf16* Qh = Qg + (size_t)bh * (SEQ * DK);
  const bf16* Kh = Kg + (size_t)bh * (SEQ * DK);
  const bf16* Vh = Vg + (size_t)bh * (SEQ * DK);

  // ---- Q fragments: direct global -> registers (q pre-scaled by QSCALE) ----
  bf16x8 qf[2];
#pragma unroll
  for (int ks = 0; ks < 2; ++ks)
    qf[ks] = *(const bf16x8*)(Qh + (size_t)qrow * DK + ks * 32 + quad * 8);

  // ---- K/V staging pointers ----
  const int krow = tid >> 3;  // 0..31 (second stripe: +32)
  const int kc8 = (tid & 7) * 8;
  const bf16* pk0 = Kh + (size_t)krow * DK + kc8;
  const bf16* pk1 = Kh + (size_t)(krow + 32) * DK + kc8;
  const int vn2 = tid & 31;   // dk-pair index
  const int vk2b = tid >> 5;  // key-pair base (k2 = vk2b + i*8)
  const bf16* pv0 = Vh + (size_t)(vk2b + 0) * 2 * DK + vn2 * 2;
  const bf16* pv1 = Vh + (size_t)(vk2b + 8) * 2 * DK + vn2 * 2;
  const bf16* pv2 = Vh + (size_t)(vk2b + 16) * 2 * DK + vn2 * 2;
  const bf16* pv3 = Vh + (size_t)(vk2b + 24) * 2 * DK + vn2 * 2;

  uint4 kr0, kr1;
  uint32_t va[4], vb[4];

  // tile 0 -> LDS
  kr0 = *(const uint4*)(pk0);
  kr1 = *(const uint4*)(pk1);
  va[0] = *(const uint32_t*)(pv0);
  vb[0] = *(const uint32_t*)(pv0 + DK);
  va[1] = *(const uint32_t*)(pv1);
  vb[1] = *(const uint32_t*)(pv1 + DK);
  va[2] = *(const uint32_t*)(pv2);
  vb[2] = *(const uint32_t*)(pv2 + DK);
  va[3] = *(const uint32_t*)(pv3);
  vb[3] = *(const uint32_t*)(pv3 + DK);
  *(uint4*)(&Ks[krow * LQ + kc8]) = kr0;
  *(uint4*)(&Ks[(krow + 32) * LQ + kc8]) = kr1;
#pragma unroll
  for (int i = 0; i < 4; ++i) {
    uint32_t t0 = (va[i] & 0xffffu) | (vb[i] << 16);
    uint32_t t1 = (va[i] >> 16) | (vb[i] & 0xffff0000u);
    *(uint32_t*)(&Vts[(vn2 * 2) * LQ + (vk2b + i * 8) * 2]) = t0;
    *(uint32_t*)(&Vts[(vn2 * 2 + 1) * LQ + (vk2b + i * 8) * 2]) = t1;
  }
  __syncthreads();  // tile 0 staged

  const f32x4 fz = {0.f, 0.f, 0.f, 0.f};
  f32x4 of_t[4];  // O^T per dk-tile
#pragma unroll
  for (int i = 0; i < 4; ++i) of_t[i] = fz;
  float lsum = 0.f;

  const unsigned* bitrow = bits + (size_t)b * SEQ * (SEQ / 32);

  for (int kt = 0; kt < 32; ++kt) {
    // prefetch next tile into registers (overlaps the whole compute body)
    if (kt + 1 < 32) {
      const size_t adv = (size_t)(kt + 1) * 64 * DK;
      kr0 = *(const uint4*)(pk0 + adv);
      kr1 = *(const uint4*)(pk1 + adv);
      va[0] = *(const uint32_t*)(pv0 + adv);
      vb[0] = *(const uint32_t*)(pv0 + adv + DK);
      va[1] = *(const uint32_t*)(pv1 + adv);
      vb[1] = *(const uint32_t*)(pv1 + adv + DK);
      va[2] = *(const uint32_t*)(pv2 + adv);
      vb[2] = *(const uint32_t*)(pv2 + adv + DK);
      va[3] = *(const uint32_t*)(pv3 + adv);
      vb[3] = *(const uint32_t*)(pv3 + adv + DK);
    }
    // mask: one 64-bit word covers this lane's q-row x this tile's 64 keys
    const uint2 mwn = *(const uint2*)(bitrow + (size_t)qrow * (SEQ / 32) + kt * 2);

    // ---- S^T = K @ Q^T (A = K-frag, B = Q-frag) ----
    f32x4 st[4];
#pragma unroll
    for (int mt = 0; mt < 4; ++mt) st[mt] = fz;
#pragma unroll
    for (int ks = 0; ks < 2; ++ks) {
#pragma unroll
      for (int mt = 0; mt < 4; ++mt) {
        bf16x8 kfv = *(const bf16x8*)(&Ks[(mt * 16 + lrow) * LQ + ks * 32 + quad * 8]);
        st[mt] = MFMA16(kfv, qf[ks], st[mt]);
      }
    }

    // ---- max-free softmax; packed b64 P stores (Ps is wave-private) ----
    {
      uint32_t ux = mwn.x >> (quad * 4);
      uint32_t uy = mwn.y >> (quad * 4);
      float psum = 0.f;
#pragma unroll
      for (int mt = 0; mt < 4; ++mt) {
        uint32_t u = (mt & 2) ? uy : ux;
        int sh = (mt & 1) << 4;
        bf16x4 pk;
#pragma unroll
        for (int r = 0; r < 4; ++r) {
          float p = EXP2(st[mt][r]);
          p = ((u >> (sh + r)) & 1u) ? p : 0.f;
          psum += p;
          pk[r] = (bf16)p;
        }
        *(bf16x4*)(&Ps[wv][lrow * LQ + mt * 16 + quad * 4]) = pk;
      }
      lsum += psum;
    }

    // ---- O^T += V^T @ P^T : A = Vt-frag, B = P-frag (both b128) ----
#pragma unroll
    for (int ks = 0; ks < 2; ++ks) {
      bf16x8 bpf = *(const bf16x8*)(&Ps[wv][lrow * LQ + ks * 32 + quad * 8]);
#pragma unroll
      for (int dkt = 0; dkt < 4; ++dkt) {
        bf16x8 avf = *(const bf16x8*)(&Vts[(dkt * 16 + lrow) * LQ + ks * 32 + quad * 8]);
        of_t[dkt] = MFMA16(avf, bpf, of_t[dkt]);
      }
    }

    __syncthreads();  // all Ks/Vts reads done
    if (kt + 1 < 32) {
      *(uint4*)(&Ks[krow * LQ + kc8]) = kr0;
      *(uint4*)(&Ks[(krow + 32) * LQ + kc8]) = kr1;
#pragma unroll
      for (int i = 0; i < 4; ++i) {
        uint32_t t0 = (va[i] & 0xffffu) | (vb[i] << 16);
        uint32_t t1 = (va[i] >> 16) | (vb[i] & 0xffff0000u);
        *(uint32_t*)(&Vts[(vn2 * 2) * LQ + (vk2b + i * 8) * 2]) = t0;
        *(uint32_t*)(&Vts[(vn2 * 2 + 1) * LQ + (vk2b + i * 8) * 2]) = t1;
      }
      __syncthreads();  // next tile staged
    }
  }

  // ---- row-sum: reduce per-lane partials across quads (2 shuffles) ----
  float v = lsum;
  v += __shfl_xor(v, 16);
  v += __shfl_xor(v, 32);
  const float linv = 1.0f / fmaxf(v, 1e-20f);

  // ---- epilogue: O^T C-layout col = q-row (lrow), row = dk (quad*4+j) ----
#pragma unroll
  for (int dkt = 0; dkt < 4; ++dkt) {
    bf16x4 o;
#pragma unroll
    for (int j = 0; j < 4; ++j) o[j] = (bf16)(of_t[dkt][j] * linv);
    *(bf16x4*)(&Y[((size_t)b * SEQ + qrow) * DIM + h * 64 + dkt * 16 + quad * 4]) = o;
  }
}

// ---------------------------------------------------------------------------
extern "C" void kernel_launch(void* const* d_in, const int* in_sizes, int n_in,
                              void* d_out, int out_size, void* d_ws, size_t ws_size,
                              hipStream_t stream) {
  const float* query = (const float*)d_in[0];
  const float* key = (const float*)d_in[1];
  const float* value = (const float*)d_in[2];
  const float* Wqkv = (const float*)d_in[3];
  const float* Wout = (const float*)d_in[4];
  const int* mask = (const int*)d_in[5];
  float* out = (float*)d_out;

  // workspace map (53 MB total; y aliases dead qin region)
  char* ws = (char*)d_ws;
  bf16* qin = (bf16*)(ws);             //  8 MB  bf16 query (dead after QKV GEMM)
  bf16* kin = (bf16*)(ws + 8388608);   //  8 MB  bf16 key
  bf16* vin = (bf16*)(ws + 16777216);  //  8 MB  bf16 value
  bf16* Wq = (bf16*)(ws + 25165824);   //  2 MB  bf16 Wqkv
  bf16* Wo = (bf16*)(ws + 27262976);   //  2 MB  bf16 Wout
  bf16* q = (bf16*)(ws + 29360128);    //  8 MB  projected q (pre-scaled)
  bf16* k = (bf16*)(ws + 37748736);    //  8 MB
  bf16* v = (bf16*)(ws + 46137344);    //  8 MB
  bf16* y = (bf16*)(ws);               //  8 MB  attn out (aliases qin)
  unsigned long long* bits64 = (unsigned long long*)(ws + 54525952);  // 1 MB

  // 1) prep: mask->bits + all fp32->bf16 converts
  prep_kernel<<<15360, 256, 0, stream>>>(mask, bits64, query, key, value, Wqkv, Wout,
                                         qin, kin, vin, Wq, Wo);

  // 2) fused QKV projection (q scaled by QSCALE in epilogue, z==0 only)
  //    128x128 blocks, 768 blocks = 3/CU (R11-best config)
  gemm_bt_lds<128, 128, 8, 32, 3, 3, bf16>
      <<<dim3(8, 32, 3), 256, 0, stream>>>(qin, kin, vin, Wq, q, k, v, QSCALE);

  // 3) flash attention v3 (32 q-tiles x 32 heads = 1024 blocks, 4/CU)
  attn_kernel<<<dim3(32, 32), 256, 0, stream>>>(q, k, v, (const unsigned*)bits64, y);

  // 4) output projection -> fp32 out; 64x128 blocks (512 blocks, 2/CU)
  gemm_bt_lds<64, 128, 8, 64, 1, 2, float>
      <<<dim3(8, 64, 1), 256, 0, stream>>>(y, y, y, Wo, out, out, out, 1.0f);
}

// Round 8
// 248.035 us; speedup vs baseline: 1.3707x; 1.0512x over previous
//
#include <hip/hip_runtime.h>
#include <stdint.h>

// ---------------------------------------------------------------------------
// MultiHeadedAttention (B=2,S=2048,D=1024,H=16,DK=64)
//   INPUTS fp32 (query,key,value,Wqkv,Wout) + int32 mask; OUTPUT fp32.
// R15:
//   * attn: exact R8 revert (R14's BQ=64 doubled staging:compute -> 97us).
//   * QKV GEMM: BM 128->64, 1536 blocks, MINW=4 (16-24 waves/CU vs 12).
//     Theory: at M=4096,N=K=1024 the m97 structure is latency/occupancy
//     starved (m102 shape curve), not LDS-throughput bound -> more waves.
//   * outproj + prep unchanged (controls).
// ---------------------------------------------------------------------------

typedef __bf16 bf16;
typedef __bf16 bf16x8 __attribute__((ext_vector_type(8)));
typedef __bf16 bf16x4 __attribute__((ext_vector_type(4)));
typedef float f32x4 __attribute__((ext_vector_type(4)));

#define MFMA16(a, b, c) __builtin_amdgcn_mfma_f32_16x16x32_bf16((a), (b), (c), 0, 0, 0)
#define EXP2(x) __builtin_amdgcn_exp2f(x)

static constexpr int BATCH = 2;
static constexpr int SEQ = 2048;
static constexpr int DIM = 1024;
static constexpr int DK = 64;
// q is pre-scaled by 1/sqrt(DK) * log2(e) in the QKV GEMM epilogue (z==0)
static constexpr float QSCALE = 0.125f * 1.44269504088896340736f;

// ---- async global->LDS, 16 B per lane -------------------------------------
__device__ inline void gload16(const void* g, void* l) {
  __builtin_amdgcn_global_load_lds((const __attribute__((address_space(1))) void*)g,
                                   (__attribute__((address_space(3))) void*)l, 16, 0, 0);
}

// ---------------- prep: mask->bits + fp32->bf16 converts (one launch) ------
// blocks [0,8192): mask bits, 4 elems/thread (wave: 256 consecutive elems).
// blocks [8192,14336): activation cvt (2048 blocks each for q,k,v).
// blocks [14336,15360): weight cvt (512 blocks each for Wqkv,Wout).
__global__ __launch_bounds__(256) void prep_kernel(
    const int* __restrict__ mask, unsigned long long* __restrict__ bits,
    const float* __restrict__ sq, const float* __restrict__ sk, const float* __restrict__ sv,
    const float* __restrict__ swq, const float* __restrict__ swo,
    bf16* __restrict__ dq, bf16* __restrict__ dk, bf16* __restrict__ dv,
    bf16* __restrict__ dwq, bf16* __restrict__ dwo) {
  const int bid = blockIdx.x;
  const int tid = threadIdx.x;
  if (bid < 8192) {
    const int lane = tid & 63, wv = tid >> 6;
    const int ebase = (bid * 4 + wv) * 256;  // 256 consecutive mask elems/wave
    unsigned long long w[4];
#pragma unroll
    for (int j = 0; j < 4; ++j) {
      int m = mask[ebase + j * 64 + lane];
      w[j] = __ballot(m != 0);
    }
    if (lane == 0) {
#pragma unroll
      for (int j = 0; j < 4; ++j) bits[(ebase >> 6) + j] = w[j];
    }
    return;
  }
  int r = bid - 8192;
  const float* s;
  bf16* d;
  int i;
  if (r < 6144) {
    s = (r < 2048) ? sq : (r < 4096) ? sk : sv;
    d = (r < 2048) ? dq : (r < 4096) ? dk : dv;
    i = (r & 2047) * 256 + tid;
  } else {
    r -= 6144;
    s = (r < 512) ? swq : swo;
    d = (r < 512) ? dwq : dwo;
    i = (r & 511) * 256 + tid;
  }
  const float4 a = ((const float4*)s)[2 * i];
  const float4 b = ((const float4*)s)[2 * i + 1];
  bf16x8 v;
  v[0] = (bf16)a.x;
  v[1] = (bf16)a.y;
  v[2] = (bf16)a.z;
  v[3] = (bf16)a.w;
  v[4] = (bf16)b.x;
  v[5] = (bf16)b.y;
  v[6] = (bf16)b.z;
  v[7] = (bf16)b.w;
  ((bf16x8*)d)[i] = v;
}

// ---------------- GEMM: C[M,1024](TC) = A[M,1024](bf16) @ W[1024,1024]^T ---
// BMxBN block, 4 waves (2x2), wave (BM/2)x(BN/2), BK=32, linear LDS [rows][32],
// global_load_lds(16B) staging, 2-phase double-buffer, XCD-chunked swizzle.
template <int BM, int BN, int NBX, int NBY, int NBZ, int MINW, typename TC>
__global__ __launch_bounds__(256, MINW) void gemm_bt_lds(
    const bf16* __restrict__ A0, const bf16* __restrict__ A1, const bf16* __restrict__ A2,
    const bf16* __restrict__ W, TC* __restrict__ C0, TC* __restrict__ C1, TC* __restrict__ C2,
    float scale0) {
  constexpr int K = 1024, N = 1024;
  constexpr int MT = BM / 32, NT = BN / 32;  // frags per wave (m,n)
  constexpr int PA = BM / 64, PB = BN / 64;  // 64-row staging passes
  constexpr int NB = NBX * NBY * NBZ;
  __shared__ __align__(16) bf16 As[2][BM * 32];
  __shared__ __align__(16) bf16 Bs[2][BN * 32];

  // bijective XCD-chunked swizzle: hw-linear id -> logical id
  const int lin = blockIdx.x + NBX * (blockIdx.y + NBY * blockIdx.z);
  const int l = (lin & 7) * (NB / 8) + (lin >> 3);
  const int lx = l % NBX;
  const int ly = (l / NBX) % NBY;
  const int lz = l / (NBX * NBY);

  const bf16* A = (lz == 0) ? A0 : (lz == 1) ? A1 : A2;
  TC* C = (lz == 0) ? C0 : (lz == 1) ? C1 : C2;
  const float sc = (lz == 0) ? scale0 : 1.0f;

  const int tid = threadIdx.x;
  const int lane = tid & 63;
  const int wv = tid >> 6;
  const int wm = wv >> 1, wn = wv & 1;
  const int lrow = lane & 15, quad = lane >> 4;
  const int m0 = ly * BM, n0 = lx * BN;

  // staging: thread t covers row (t>>2) of each 64-row stripe, 8 bf16 at (t&3)*8
  const int r0 = tid >> 2, c0 = (tid & 3) * 8;
  const bf16* pa[PA];
  const bf16* pb[PB];
#pragma unroll
  for (int p = 0; p < PA; ++p) pa[p] = A + (size_t)(m0 + p * 64 + r0) * K + c0;
#pragma unroll
  for (int p = 0; p < PB; ++p) pb[p] = W + (size_t)(n0 + p * 64 + r0) * K + c0;

  const f32x4 fz = {0.f, 0.f, 0.f, 0.f};
  f32x4 acc[MT][NT];
#pragma unroll
  for (int i = 0; i < MT; ++i)
#pragma unroll
    for (int j = 0; j < NT; ++j) acc[i][j] = fz;

  // prologue: stage tile 0 into buffer 0
#pragma unroll
  for (int p = 0; p < PA; ++p) gload16(pa[p], &As[0][p * 2048 + tid * 8]);
#pragma unroll
  for (int p = 0; p < PB; ++p) gload16(pb[p], &Bs[0][p * 2048 + tid * 8]);
  __syncthreads();  // vmcnt(0): tile 0 resident

  for (int t = 0; t < K / 32; ++t) {
    const int cur = t & 1;
    if (t + 1 < K / 32) {  // issue next-tile prefetch into the other buffer
      const int k1 = (t + 1) * 32;
#pragma unroll
      for (int p = 0; p < PA; ++p) gload16(pa[p] + k1, &As[cur ^ 1][p * 2048 + tid * 8]);
#pragma unroll
      for (int p = 0; p < PB; ++p) gload16(pb[p] + k1, &Bs[cur ^ 1][p * 2048 + tid * 8]);
    }
    bf16x8 af[MT], bfr[NT];
#pragma unroll
    for (int mt = 0; mt < MT; ++mt)
      af[mt] = *(const bf16x8*)(&As[cur][(wm * (BM / 2) + mt * 16 + lrow) * 32 + quad * 8]);
#pragma unroll
    for (int nt = 0; nt < NT; ++nt)
      bfr[nt] = *(const bf16x8*)(&Bs[cur][(wn * (BN / 2) + nt * 16 + lrow) * 32 + quad * 8]);
#pragma unroll
    for (int mt = 0; mt < MT; ++mt)
#pragma unroll
      for (int nt = 0; nt < NT; ++nt) acc[mt][nt] = MFMA16(af[mt], bfr[nt], acc[mt][nt]);
    __syncthreads();  // drains this step's prefetch + all ds reads
  }

#pragma unroll
  for (int mt = 0; mt < MT; ++mt) {
    const int gm = m0 + wm * (BM / 2) + mt * 16 + quad * 4;
#pragma unroll
    for (int nt = 0; nt < NT; ++nt) {
      const int gn = n0 + wn * (BN / 2) + nt * 16 + lrow;
#pragma unroll
      for (int r = 0; r < 4; ++r) C[(size_t)(gm + r) * N + gn] = (TC)(acc[mt][nt][r] * sc);
    }
  }
}

// ---------------- flash attention, transposed-S form (R8 exact) ------------
// BQ=128/block (4 waves x 32 q-rows), K-tiles of 64, max-free softmax.
// S^T = K·Q^T: per-lane P = 4 consecutive keys at one q-row -> b64 stores.
// Double-buffered K/V LDS (Qs reused as buffer 1), one barrier per tile.
__global__ __launch_bounds__(256, 2) void attn_kernel(const bf16* __restrict__ Qg,
                                                      const bf16* __restrict__ Kg,
                                                      const bf16* __restrict__ Vg,
                                                      const unsigned* __restrict__ bits,
                                                      bf16* __restrict__ Y) {
  constexpr int LQ = 72;
  __shared__ bf16 Qs[128 * LQ];  // after qf extraction: K/V buffer 1
  __shared__ bf16 Ks[64 * LQ];
  __shared__ bf16 Vts[64 * LQ];
  __shared__ bf16 Ps[4][32 * LQ];

  const int tid = threadIdx.x;
  const int lane = tid & 63;
  const int wv = tid >> 6;
  const int lrow = lane & 15, quad = lane >> 4;
  const int bh = blockIdx.y;
  const int b = bh >> 4, h = bh & 15;
  const int q0 = blockIdx.x * 128;

  const bf16* Qh = Qg + (size_t)bh * (SEQ * DK);
  const bf16* Kh = Kg + (size_t)bh * (SEQ * DK);
  const bf16* Vh = Vg + (size_t)bh * (SEQ * DK);

  // ---- stage Q tile (128x64, pre-scaled by QSCALE) ----
#pragma unroll
  for (int i = 0; i < 4; ++i) {
    int s = tid + i * 256;
    int row = s >> 3, c8 = (s & 7) * 8;
    *(uint4*)(&Qs[row * LQ + c8]) = *(const uint4*)(Qh + (size_t)(q0 + row) * DK + c8);
  }

  // ---- K/V prefetch-register plumbing ----
  const int krow = tid >> 3;  // 0..31 (second stripe: +32)
  const int kc8 = (tid & 7) * 8;
  const bf16* pk0 = Kh + (size_t)krow * DK + kc8;
  const bf16* pk1 = Kh + (size_t)(krow + 32) * DK + kc8;
  const int vn2 = tid & 31;   // dk-pair index
  const int vk2b = tid >> 5;  // key-pair base (k2 = vk2b + i*8)
  const bf16* pv0 = Vh + (size_t)(vk2b + 0) * 2 * DK + vn2 * 2;
  const bf16* pv1 = Vh + (size_t)(vk2b + 8) * 2 * DK + vn2 * 2;
  const bf16* pv2 = Vh + (size_t)(vk2b + 16) * 2 * DK + vn2 * 2;
  const bf16* pv3 = Vh + (size_t)(vk2b + 24) * 2 * DK + vn2 * 2;

  uint4 kr0, kr1;
  uint32_t va[4], vb[4];

  // tile 0 -> buffer 0 (Ks/Vts; independent of Qs)
  kr0 = *(const uint4*)(pk0);
  kr1 = *(const uint4*)(pk1);
  va[0] = *(const uint32_t*)(pv0);
  vb[0] = *(const uint32_t*)(pv0 + DK);
  va[1] = *(const uint32_t*)(pv1);
  vb[1] = *(const uint32_t*)(pv1 + DK);
  va[2] = *(const uint32_t*)(pv2);
  vb[2] = *(const uint32_t*)(pv2 + DK);
  va[3] = *(const uint32_t*)(pv3);
  vb[3] = *(const uint32_t*)(pv3 + DK);
  *(uint4*)(&Ks[krow * LQ + kc8]) = kr0;
  *(uint4*)(&Ks[(krow + 32) * LQ + kc8]) = kr1;
#pragma unroll
  for (int i = 0; i < 4; ++i) {
    uint32_t t0 = (va[i] & 0xffffu) | (vb[i] << 16);
    uint32_t t1 = (va[i] >> 16) | (vb[i] & 0xffff0000u);
    *(uint32_t*)(&Vts[(vn2 * 2) * LQ + (vk2b + i * 8) * 2]) = t0;
    *(uint32_t*)(&Vts[(vn2 * 2 + 1) * LQ + (vk2b + i * 8) * 2]) = t1;
  }
  __syncthreads();  // Q + tile0 staged

  bf16x8 qf[2][2];  // B-frag for S^T: [q-row tile][ks]
#pragma unroll
  for (int nt = 0; nt < 2; ++nt)
#pragma unroll
    for (int ks = 0; ks < 2; ++ks)
      qf[nt][ks] = *(const bf16x8*)(&Qs[(wv * 32 + nt * 16 + lrow) * LQ + ks * 32 + quad * 8]);
  __syncthreads();  // all qf reads done -> Qs reusable as buffer 1

  const f32x4 fz = {0.f, 0.f, 0.f, 0.f};
  f32x4 of_t[4][2];  // O^T: [dk-tile][q-row-tile]
#pragma unroll
  for (int i = 0; i < 4; ++i)
#pragma unroll
    for (int j = 0; j < 2; ++j) of_t[i][j] = fz;
  float lsum[2] = {0.f, 0.f};  // per-lane partial row sums (q-row nt*16+lrow)

  const unsigned* bitrow = bits + (size_t)b * SEQ * (SEQ / 32);

  for (int kt = 0; kt < 32; ++kt) {
    const int cur = kt & 1;
    bf16* kb = cur ? Qs : Ks;
    bf16* vbuf = cur ? (Qs + 64 * LQ) : Vts;
    // prefetch next tile (global; overlaps the whole compute body)
    if (kt + 1 < 32) {
      const size_t adv = (size_t)(kt + 1) * 64 * DK;
      kr0 = *(const uint4*)(pk0 + adv);
      kr1 = *(const uint4*)(pk1 + adv);
      va[0] = *(const uint32_t*)(pv0 + adv);
      vb[0] = *(const uint32_t*)(pv0 + adv + DK);
      va[1] = *(const uint32_t*)(pv1 + adv);
      vb[1] = *(const uint32_t*)(pv1 + adv + DK);
      va[2] = *(const uint32_t*)(pv2 + adv);
      vb[2] = *(const uint32_t*)(pv2 + adv + DK);
      va[3] = *(const uint32_t*)(pv3 + adv);
      vb[3] = *(const uint32_t*)(pv3 + adv + DK);
    }
    // mask: one 64-bit word per q-row covers this tile's 64 keys
    uint2 mwn[2];
#pragma unroll
    for (int nt = 0; nt < 2; ++nt) {
      int row = q0 + wv * 32 + nt * 16 + lrow;
      mwn[nt] = *(const uint2*)(bitrow + (size_t)row * (SEQ / 32) + kt * 2);
    }

    // ---- S^T = K @ Q^T (A = K-frag, B = Q-frag) ----
    f32x4 st[4][2];
#pragma unroll
    for (int mt = 0; mt < 4; ++mt)
#pragma unroll
      for (int nt = 0; nt < 2; ++nt) st[mt][nt] = fz;
#pragma unroll
    for (int ks = 0; ks < 2; ++ks) {
#pragma unroll
      for (int mt = 0; mt < 4; ++mt) {
        bf16x8 kfv = *(const bf16x8*)(kb + (mt * 16 + lrow) * LQ + ks * 32 + quad * 8);
#pragma unroll
        for (int nt = 0; nt < 2; ++nt) st[mt][nt] = MFMA16(kfv, qf[nt][ks], st[mt][nt]);
      }
    }

    // ---- max-free softmax; packed b64 P stores ----
    // lane's values: q-row = nt*16+lrow, keys = mt*16+quad*4+{0..3}
#pragma unroll
    for (int nt = 0; nt < 2; ++nt) {
      uint32_t ux = mwn[nt].x >> (quad * 4);
      uint32_t uy = mwn[nt].y >> (quad * 4);
      float psum = 0.f;
#pragma unroll
      for (int mt = 0; mt < 4; ++mt) {
        uint32_t u = (mt & 2) ? uy : ux;
        int sh = (mt & 1) << 4;
        bf16x4 pk;
#pragma unroll
        for (int r = 0; r < 4; ++r) {
          float p = EXP2(st[mt][nt][r]);
          p = ((u >> (sh + r)) & 1u) ? p : 0.f;
          psum += p;
          pk[r] = (bf16)p;
        }
        *(bf16x4*)(&Ps[wv][(nt * 16 + lrow) * LQ + mt * 16 + quad * 4]) = pk;
      }
      lsum[nt] += psum;
    }

    // ---- O^T += V^T @ P^T : A = Vt-frag, B = P-frag (both b128) ----
#pragma unroll
    for (int ks = 0; ks < 2; ++ks) {
      bf16x8 avf[4], bpf[2];
#pragma unroll
      for (int dkt = 0; dkt < 4; ++dkt)
        avf[dkt] = *(const bf16x8*)(vbuf + (dkt * 16 + lrow) * LQ + ks * 32 + quad * 8);
#pragma unroll
      for (int rt = 0; rt < 2; ++rt)
        bpf[rt] = *(const bf16x8*)(&Ps[wv][(rt * 16 + lrow) * LQ + ks * 32 + quad * 8]);
#pragma unroll
      for (int dkt = 0; dkt < 4; ++dkt)
#pragma unroll
        for (int rt = 0; rt < 2; ++rt) of_t[dkt][rt] = MFMA16(avf[dkt], bpf[rt], of_t[dkt][rt]);
    }

    // stage next tile into the other buffer
    if (kt + 1 < 32) {
      bf16* kbn = cur ? Ks : Qs;
      bf16* vbn = cur ? Vts : (Qs + 64 * LQ);
      *(uint4*)(kbn + krow * LQ + kc8) = kr0;
      *(uint4*)(kbn + (krow + 32) * LQ + kc8) = kr1;
#pragma unroll
      for (int i = 0; i < 4; ++i) {
        uint32_t t0 = (va[i] & 0xffffu) | (vb[i] << 16);
        uint32_t t1 = (va[i] >> 16) | (vb[i] & 0xffff0000u);
        *(uint32_t*)(vbn + (vn2 * 2) * LQ + (vk2b + i * 8) * 2) = t0;
        *(uint32_t*)(vbn + (vn2 * 2 + 1) * LQ + (vk2b + i * 8) * 2) = t1;
      }
    }
    __syncthreads();  // single barrier per tile
  }

  // ---- row-sum: reduce per-lane partials across quads (2 shuffles) ----
  float linv[2];
#pragma unroll
  for (int nt = 0; nt < 2; ++nt) {
    float v = lsum[nt];
    v += __shfl_xor(v, 16);
    v += __shfl_xor(v, 32);
    linv[nt] = 1.0f / fmaxf(v, 1e-20f);
  }

  // ---- epilogue: O^T C-layout col = q-row (lrow), row = dk (quad*4+j) ----
#pragma unroll
  for (int dkt = 0; dkt < 4; ++dkt)
#pragma unroll
    for (int rt = 0; rt < 2; ++rt) {
      bf16x4 o;
#pragma unroll
      for (int j = 0; j < 4; ++j) o[j] = (bf16)(of_t[dkt][rt][j] * linv[rt]);
      const int row = q0 + wv * 32 + rt * 16 + lrow;
      *(bf16x4*)(&Y[((size_t)b * SEQ + row) * DIM + h * 64 + dkt * 16 + quad * 4]) = o;
    }
}

// ---------------------------------------------------------------------------
extern "C" void kernel_launch(void* const* d_in, const int* in_sizes, int n_in,
                              void* d_out, int out_size, void* d_ws, size_t ws_size,
                              hipStream_t stream) {
  const float* query = (const float*)d_in[0];
  const float* key = (const float*)d_in[1];
  const float* value = (const float*)d_in[2];
  const float* Wqkv = (const float*)d_in[3];
  const float* Wout = (const float*)d_in[4];
  const int* mask = (const int*)d_in[5];
  float* out = (float*)d_out;

  // workspace map (53 MB total; y aliases dead qin region)
  char* ws = (char*)d_ws;
  bf16* qin = (bf16*)(ws);             //  8 MB  bf16 query (dead after QKV GEMM)
  bf16* kin = (bf16*)(ws + 8388608);   //  8 MB  bf16 key
  bf16* vin = (bf16*)(ws + 16777216);  //  8 MB  bf16 value
  bf16* Wq = (bf16*)(ws + 25165824);   //  2 MB  bf16 Wqkv
  bf16* Wo = (bf16*)(ws + 27262976);   //  2 MB  bf16 Wout
  bf16* q = (bf16*)(ws + 29360128);    //  8 MB  projected q (pre-scaled)
  bf16* k = (bf16*)(ws + 37748736);    //  8 MB
  bf16* v = (bf16*)(ws + 46137344);    //  8 MB
  bf16* y = (bf16*)(ws);               //  8 MB  attn out (aliases qin)
  unsigned long long* bits64 = (unsigned long long*)(ws + 54525952);  // 1 MB

  // 1) prep: mask->bits + all fp32->bf16 converts
  prep_kernel<<<15360, 256, 0, stream>>>(mask, bits64, query, key, value, Wqkv, Wout,
                                         qin, kin, vin, Wq, Wo);

  // 2) fused QKV projection (q scaled by QSCALE in epilogue, z==0 only)
  //    64x128 blocks -> 1536 blocks, MINW=4 (occupancy bet)
  gemm_bt_lds<64, 128, 8, 64, 3, 4, bf16>
      <<<dim3(8, 64, 3), 256, 0, stream>>>(qin, kin, vin, Wq, q, k, v, QSCALE);

  // 3) flash attention (16 q-tiles x 32 heads, R8-exact)
  attn_kernel<<<dim3(16, 32), 256, 0, stream>>>(q, k, v, (const unsigned*)bits64, y);

  // 4) output projection -> fp32 out; 64x128 blocks (512 blocks, 2/CU)
  gemm_bt_lds<64, 128, 8, 64, 1, 2, float>
      <<<dim3(8, 64, 1), 256, 0, stream>>>(y, y, y, Wo, out, out, out, 1.0f);
}